// Round 1
// baseline (193.403 us; speedup 1.0000x reference)
//
#include <hip/hip_runtime.h>
#include <stdint.h>

// Problem constants (match reference setup_inputs: N=4096, D=256, C=1000)
#define NR 4096
#define DD 256
#define NC_TOT 4096000          // N*C elements in pred/target
#define TILES 32                // 4096 / 128
#define NTRI 528                // TILES*(TILES+1)/2
#define BK 32                   // K-chunk per LDS stage (8 chunks of 32 over K=256)

typedef __bf16 bf16x8 __attribute__((ext_vector_type(8)));
typedef float f32x4 __attribute__((ext_vector_type(4)));
typedef unsigned short u16;

// ws layout:
//   [0,16)           float acc[4] = {label_sse, featsum0, featsum1, featsum2}
//   [1024, +6*4096*4)  fp32 row sq-norms, 6 matrices (pred_f0..2, target_f0..2)
//   [131072, +6*4096*256*2) bf16 feature data, same order
#define WS_SQN_OFF  1024
#define WS_BF16_OFF 131072

__device__ __forceinline__ u16 f2bf(float x) {
    uint32_t u = __float_as_uint(x);
    u += 0x7FFFu + ((u >> 16) & 1u);   // round-to-nearest-even
    return (u16)(u >> 16);
}

// ---------------- prep: fp32 -> bf16 + row sq-norm (one wave per row) -----
__global__ __launch_bounds__(256) void prep_kernel(
    const float* __restrict__ m0, const float* __restrict__ m1,
    const float* __restrict__ m2, const float* __restrict__ m3,
    const float* __restrict__ m4, const float* __restrict__ m5,
    u16* __restrict__ bf, float* __restrict__ sqn)
{
    const float* mats[6] = {m0, m1, m2, m3, m4, m5};
    int w = threadIdx.x >> 6, lane = threadIdx.x & 63;
    int row_id = blockIdx.x * 4 + w;        // 6*4096 rows total
    int m = row_id >> 12;                   // /4096  (wave-uniform)
    int r = row_id & 4095;
    const float4* src = (const float4*)(mats[m] + (size_t)r * DD);
    u16* dst = bf + ((size_t)m * NR + r) * DD;
    float4 v = src[lane];
    float ss = v.x * v.x + v.y * v.y + v.z * v.z + v.w * v.w;
    ushort4 o;
    o.x = f2bf(v.x); o.y = f2bf(v.y); o.z = f2bf(v.z); o.w = f2bf(v.w);
    ((ushort4*)dst)[lane] = o;
    #pragma unroll
    for (int off = 32; off; off >>= 1) ss += __shfl_down(ss, off);
    if (lane == 0) sqn[(size_t)m * NR + r] = ss;
}

// ---------------- fused Gram + pairwise-L2 + MSE-sum, triangular tiles ----
__global__ __launch_bounds__(256) void gram_loss_kernel(
    const u16* __restrict__ bf, const float* __restrict__ sqn,
    float* __restrict__ acc)
{
    __shared__ u16 tile[4][128][BK];     // Ap, Bp, At, Bt : 32 KB
    __shared__ float s_sqn[4][128];      // sqn_p[i], sqn_p[j], sqn_t[i], sqn_t[j]
    __shared__ float s_red[4];

    const int f = blockIdx.y;
    // decode linear triangular index -> (ti, tj), ti <= tj
    int ti = 0, rem = blockIdx.x;
    while (rem >= TILES - ti) { rem -= TILES - ti; ti++; }
    const int tj = ti + rem;

    const int t = threadIdx.x;
    const int w = t >> 6, lane = t & 63;
    const int wm = w >> 1, wn = w & 1;          // 2x2 waves -> 128x128 tile
    const int quad = lane >> 4, l16 = lane & 15;

    const u16* matp = bf + (size_t)f * (NR * DD);
    const u16* matt = bf + (size_t)(3 + f) * (NR * DD);
    const float* sqp = sqn + (size_t)f * NR;
    const float* sqt = sqn + (size_t)(3 + f) * NR;

    // stage the 4x128 sq-norm slices
    for (int i = t; i < 512; i += 256) {
        int which = i >> 7, r = i & 127;
        const float* sp = (which < 2) ? sqp : sqt;
        int trow = (which & 1) ? tj : ti;
        s_sqn[which][r] = sp[trow * 128 + r];
    }

    f32x4 accp[4][4], acct[4][4];
    #pragma unroll
    for (int a = 0; a < 4; a++)
        #pragma unroll
        for (int b = 0; b < 4; b++) {
            accp[a][b] = f32x4{0.f, 0.f, 0.f, 0.f};
            acct[a][b] = f32x4{0.f, 0.f, 0.f, 0.f};
        }

    const u16* srcmat[4] = {matp, matp, matt, matt};
    const int srow[4] = {ti * 128, tj * 128, ti * 128, tj * 128};

    for (int kc = 0; kc < DD / BK; kc++) {
        // ---- stage 4 tiles of 128 x BK bf16 via global_load_lds (16B/lane)
        #pragma unroll
        for (int m = 0; m < 4; m++) {
            const char* gbase = (const char*)srcmat[m] +
                                (size_t)srow[m] * (DD * 2) + kc * (BK * 2);
            char* lbase = (char*)&tile[m][0][0];
            #pragma unroll
            for (int p = 0; p < 2; p++) {
                int o = p * 4096 + t * 16;          // byte offset in 8 KB tile
                int row = o >> 6;                   // 64 B per LDS row
                int colb = o & 63;
                const char* gp = gbase + (size_t)row * (DD * 2) + colb;
                char* lp = lbase + p * 4096 + (t & 192) * 16;  // wave-uniform base
                __builtin_amdgcn_global_load_lds(
                    (const __attribute__((address_space(1))) void*)gp,
                    (__attribute__((address_space(3))) void*)lp, 16, 0, 0);
            }
        }
        __syncthreads();   // drains vmcnt before barrier

        // ---- MFMA: one 32-wide K slab; pred then target
        const int col = quad * 8;
        bf16x8 afr[4], bfr[4];
        #pragma unroll
        for (int mi = 0; mi < 4; mi++)
            afr[mi] = *(const bf16x8*)&tile[0][wm * 64 + mi * 16 + l16][col];
        #pragma unroll
        for (int ni = 0; ni < 4; ni++)
            bfr[ni] = *(const bf16x8*)&tile[1][wn * 64 + ni * 16 + l16][col];
        #pragma unroll
        for (int mi = 0; mi < 4; mi++)
            #pragma unroll
            for (int ni = 0; ni < 4; ni++)
                accp[mi][ni] = __builtin_amdgcn_mfma_f32_16x16x32_bf16(
                    afr[mi], bfr[ni], accp[mi][ni], 0, 0, 0);
        #pragma unroll
        for (int mi = 0; mi < 4; mi++)
            afr[mi] = *(const bf16x8*)&tile[2][wm * 64 + mi * 16 + l16][col];
        #pragma unroll
        for (int ni = 0; ni < 4; ni++)
            bfr[ni] = *(const bf16x8*)&tile[3][wn * 64 + ni * 16 + l16][col];
        #pragma unroll
        for (int mi = 0; mi < 4; mi++)
            #pragma unroll
            for (int ni = 0; ni < 4; ni++)
                acct[mi][ni] = __builtin_amdgcn_mfma_f32_16x16x32_bf16(
                    afr[mi], bfr[ni], acct[mi][ni], 0, 0, 0);
        __syncthreads();   // before next stage overwrites LDS
    }

    // ---- epilogue: dist_p, dist_t, (dp-dt)^2, accumulate
    // C/D layout: col = lane&15, row = quad*4 + reg   [m89/m91 verified]
    float local = 0.f;
    const int gi_base = ti * 128, gj_base = tj * 128;
    #pragma unroll
    for (int mi = 0; mi < 4; mi++) {
        const int i0 = wm * 64 + mi * 16 + quad * 4;
        #pragma unroll
        for (int ni = 0; ni < 4; ni++) {
            const int j_loc = wn * 64 + ni * 16 + l16;
            const float spj = s_sqn[1][j_loc], stj = s_sqn[3][j_loc];
            #pragma unroll
            for (int r = 0; r < 4; r++) {
                const int i_loc = i0 + r;
                float dp2 = s_sqn[0][i_loc] + spj - 2.f * accp[mi][ni][r];
                float dt2 = s_sqn[2][i_loc] + stj - 2.f * acct[mi][ni][r];
                float dp = (dp2 > 0.f) ? sqrtf(dp2) : 0.f;
                float dt = (dt2 > 0.f) ? sqrtf(dt2) : 0.f;
                if (gi_base + i_loc == gj_base + j_loc) { dp = 0.f; dt = 0.f; }
                float d = dp - dt;
                local += d * d;
            }
        }
    }
    local *= (ti == tj) ? 1.f : 2.f;   // symmetric: off-diagonal tiles count twice
    #pragma unroll
    for (int off = 32; off; off >>= 1) local += __shfl_down(local, off);
    if (lane == 0) s_red[w] = local;
    __syncthreads();
    if (t == 0) atomicAdd(&acc[1 + f], s_red[0] + s_red[1] + s_red[2] + s_red[3]);
}

// ---------------- label MSE (sum of squared diff) -------------------------
__global__ __launch_bounds__(256) void mse_kernel(
    const float4* __restrict__ a, const float4* __restrict__ b,
    float* __restrict__ acc, int n4)
{
    int i = blockIdx.x * blockDim.x + threadIdx.x;
    const int stride = gridDim.x * blockDim.x;
    float s = 0.f;
    for (; i < n4; i += stride) {
        float4 x = a[i], y = b[i];
        float dx = x.x - y.x, dy = x.y - y.y, dz = x.z - y.z, dw = x.w - y.w;
        s += dx * dx + dy * dy + dz * dz + dw * dw;
    }
    #pragma unroll
    for (int off = 32; off; off >>= 1) s += __shfl_down(s, off);
    __shared__ float sr[4];
    int w = threadIdx.x >> 6, lane = threadIdx.x & 63;
    if (lane == 0) sr[w] = s;
    __syncthreads();
    if (threadIdx.x == 0) atomicAdd(&acc[0], sr[0] + sr[1] + sr[2] + sr[3]);
}

// ---------------- final combine ------------------------------------------
__global__ void finalize_kernel(const float* __restrict__ acc,
                                float* __restrict__ out)
{
    if (threadIdx.x == 0 && blockIdx.x == 0) {
        float label = acc[0] / (float)NC_TOT;
        float feat = (acc[1] + acc[2] + acc[3]) / ((float)NR * (float)NR);
        out[0] = 0.2f * label + (0.8f / 3.0f) * feat;
    }
}

extern "C" void kernel_launch(void* const* d_in, const int* in_sizes, int n_in,
                              void* d_out, int out_size, void* d_ws, size_t ws_size,
                              hipStream_t stream) {
    const float* pred   = (const float*)d_in[0];
    const float* target = (const float*)d_in[1];

    float* acc = (float*)d_ws;
    float* sqn = (float*)((char*)d_ws + WS_SQN_OFF);
    u16* bf    = (u16*)((char*)d_ws + WS_BF16_OFF);

    hipMemsetAsync(d_ws, 0, 16, stream);   // zero the 4 accumulators

    prep_kernel<<<6 * NR / 4, 256, 0, stream>>>(
        (const float*)d_in[2], (const float*)d_in[3], (const float*)d_in[4],
        (const float*)d_in[5], (const float*)d_in[6], (const float*)d_in[7],
        bf, sqn);

    gram_loss_kernel<<<dim3(NTRI, 3), 256, 0, stream>>>(bf, sqn, acc);

    mse_kernel<<<1024, 256, 0, stream>>>(
        (const float4*)pred, (const float4*)target, acc, NC_TOT / 4);

    finalize_kernel<<<1, 64, 0, stream>>>(acc, (float*)d_out);
}